// Round 2
// baseline (73338.611 us; speedup 1.0000x reference)
//
// SCN-LSTM persistent-kernel implementation for MI355X (gfx950).
//
// Round 3:
//  - BUGFIX: prep_xbf16 loop bound was 2x too large (8388608 groups-of-8 vs the
//    correct 4194304) -> wrote 67MB past ws / read 128MB past inps -> GPU page
//    fault -> container crash. This, not the barrier, killed round 2.
//  - Residency hardening: phase-B weights now live in 128 VGPRs/lane (statically
//    indexed, fully unrolled) and phase-A weights in 64KB LDS (read-order
//    layout, conflict-free ds_read_b128). Total LDS 68KB + launch_bounds(256,2)
//    -> 2 blocks/CU schedulable, so the 256-block grid is co-resident even with
//    CUs reserved (round-2's 132KB LDS required exactly 256 free CUs).
//  - Distributed arrive-flags barrier kept; polling now wave-0-only (4 flags
//    per lane, one coalesced line per poll round) with a block-uniform timeout
//    bail (2^20 polls ~ 0.4s) so a lost block can never hang the harness.
//  - Per-tick weight traffic (16MB/tick L2-thrash in round 1) is now zero.
#include <hip/hip_runtime.h>

typedef unsigned short u16;
typedef __attribute__((ext_vector_type(8))) short s16x8;
typedef __attribute__((ext_vector_type(4))) float f32x4;
typedef __attribute__((ext_vector_type(4))) float float4v;

#define T_ 1024
#define OUT_HST 33554432   // 64*1024*512
#define OUT_CST 33619968   // + 64*2*512

// workspace byte offsets
#define WT_BYTES   (1u << 21)                // 2MB per transposed weight tensor (4x512x512 bf16)
#define OFF_SC     (8u * WT_BYTES)           // 16,777,216 : tb0, ub0, ub1, tb1 (4x4x64x512 f32)
#define OFF_P      (OFF_SC + 2097152u)       // 18,874,368 : P0..P3 (4 x 4x64x512 bf16)
#define OFF_HST    (OFF_P + 1048576u)        // 19,922,944 : h state, 2 layers, bf16
#define OFF_CSTATE (OFF_HST + 131072u)       // 20,054,016 : c state, 2 layers, f32
#define OFF_BAR    (OFF_CSTATE + 262144u)    // 20,316,160 : barrier flags (256 u32)
#define OFF_XBF    (OFF_BAR + 4096u)         // 20,320,256 : inps as bf16 (optional)
#define XBF_BYTES  67108864ull               // 64*1024*512*2

__device__ __forceinline__ u16 f2bf(float f) {
  union { float f; unsigned u; } v; v.f = f;
  return (u16)((v.u + 0x7FFFu + ((v.u >> 16) & 1u)) >> 16);
}

__device__ __forceinline__ s16x8 cvt8(const float* p) {
  float4v a = *(const float4v*)p;
  float4v b = *(const float4v*)(p + 4);
  s16x8 r;
  r[0] = (short)f2bf(a[0]); r[1] = (short)f2bf(a[1]);
  r[2] = (short)f2bf(a[2]); r[3] = (short)f2bf(a[3]);
  r[4] = (short)f2bf(b[0]); r[5] = (short)f2bf(b[1]);
  r[6] = (short)f2bf(b[2]); r[7] = (short)f2bf(b[3]);
  return r;
}

__device__ __forceinline__ f32x4 mfma_bf16(s16x8 a, s16x8 b, f32x4 c) {
  return __builtin_amdgcn_mfma_f32_16x16x32_bf16(a, b, c, 0, 0, 0);
}

// ---------------- prep kernels ----------------

struct SrcPtrs { const float* p[8]; };

// Transpose 8 weight tensors (4,512,512) f32 [g][k][n] -> (4,512,512) bf16 [g][n][k]
__global__ void prep_transpose(SrcPtrs s, unsigned char* ws) {
  __shared__ float tb[64][65];
  int bid = blockIdx.x, tid = threadIdx.x;
  int ten = bid >> 8, g = (bid >> 6) & 3, tile = bid & 63;
  int tk = (tile >> 3) << 6, tn = (tile & 7) << 6;
  const float* src = s.p[ten] + ((size_t)g << 18);
  u16* dst = (u16*)(ws + (size_t)ten * WT_BYTES) + ((size_t)g << 18);
  int c = tid & 63, i0 = tid >> 6;
  for (int i = i0; i < 64; i += 4)
    tb[i][c] = src[(size_t)(tk + i) * 512 + tn + c];
  __syncthreads();
  for (int i = i0; i < 64; i += 4)
    dst[(size_t)(tn + i) * 512 + tk + c] = f2bf(tb[c][i]);
}

// SC[m][g][b][f] = sum_k tag[b][k] * W_m[g][k][f], K=300.  m: tb0, ub0, ub1, tb1
__global__ void prep_scales(const float* tag, const float* w0, const float* w1,
                            const float* w2, const float* w3, unsigned char* ws) {
  int t = blockIdx.x * 256 + threadIdx.x;
  int f = t & 511, b = (t >> 9) & 63, g = (t >> 15) & 3, m = t >> 17;
  const float* W = (m == 0) ? w0 : (m == 1) ? w1 : (m == 2) ? w2 : w3;
  const float* tg = tag + b * 300;
  const float* wp = W + (size_t)(g * 300) * 512 + f;
  float acc = 0.f;
  for (int k = 0; k < 300; ++k) acc += tg[k] * wp[(size_t)k * 512];
  ((float*)(ws + OFF_SC))[((size_t)(m * 4 + g) * 64 + b) * 512 + f] = acc;
}

// init h/c state + barrier flags
__global__ void prep_state(const float* hh, const float* hc, unsigned char* ws) {
  int t = blockIdx.x * 256 + threadIdx.x;  // 0..65535
  u16* H = (u16*)(ws + OFF_HST);
  float* C = (float*)(ws + OFF_CSTATE);
  unsigned* bar = (unsigned*)(ws + OFF_BAR);
  if (t < 1024) bar[t] = 0u;
  int L = t >> 15, r = t & 32767;
  int b = r >> 9, h = r & 511;
  float hv = hh[(size_t)b * 1024 + L * 512 + h];
  float cv = hc[(size_t)b * 1024 + L * 512 + h];
  H[t] = f2bf(hv);
  C[t] = cv;
}

// convert inps (64,1024,512) f32 -> bf16 in ws (same layout).
// 33,554,432 elements = 4,194,304 groups of 8.  (Round-2 bug: bound was 2x.)
__global__ void prep_xbf16(const float* __restrict__ inps, unsigned char* ws) {
  u16* dst = (u16*)(ws + OFF_XBF);
  size_t stride = (size_t)gridDim.x * blockDim.x;
  for (size_t i = (size_t)blockIdx.x * blockDim.x + threadIdx.x; i < 4194304ull;
       i += stride)
    *(s16x8*)(dst + i * 8) = cvt8(inps + i * 8);
}

// ---------------- persistent kernel ----------------

// Distributed arrive-flags barrier: block b publishes flags[b]=phase (release);
// wave 0 polls all 256 flags (4 per lane, one coalesced line per round).
// Timeout propagates block-uniformly through *okflag (shared) -> clean bail.
__device__ __forceinline__ bool gridbar(unsigned* flags, unsigned phase,
                                        int* okflag) {
  __syncthreads();
  if (threadIdx.x == 0) {
    __threadfence();  // make this block's P/H/C/out writes agent-visible
    __hip_atomic_store(flags + blockIdx.x, phase, __ATOMIC_RELEASE,
                       __HIP_MEMORY_SCOPE_AGENT);
  }
  if (threadIdx.x < 64) {
    const unsigned* fp = flags + threadIdx.x * 4;
    long spin = 0;
    for (;;) {
      unsigned a = __hip_atomic_load(fp + 0, __ATOMIC_RELAXED, __HIP_MEMORY_SCOPE_AGENT);
      unsigned b = __hip_atomic_load(fp + 1, __ATOMIC_RELAXED, __HIP_MEMORY_SCOPE_AGENT);
      unsigned c = __hip_atomic_load(fp + 2, __ATOMIC_RELAXED, __HIP_MEMORY_SCOPE_AGENT);
      unsigned d = __hip_atomic_load(fp + 3, __ATOMIC_RELAXED, __HIP_MEMORY_SCOPE_AGENT);
      if (a >= phase && b >= phase && c >= phase && d >= phase) break;
      __builtin_amdgcn_s_sleep(2);
      if (++spin > (1L << 20)) { *okflag = 0; break; }  // ~0.4s: bail, don't hang
    }
  }
  __threadfence();
  __syncthreads();
  return *okflag != 0;
}

__global__ __launch_bounds__(256, 2) void scn_persistent(
    const float* __restrict__ inps, const float* __restrict__ bias0,
    const float* __restrict__ bias1, unsigned char* __restrict__ ws,
    float* __restrict__ out, int use_xbf) {
  const int tid = threadIdx.x;
  const int wave = tid >> 6, lane = tid & 63, q = lane >> 4, l16 = lane & 15;
  const int bid = blockIdx.x;

  u16* P = (u16*)(ws + OFF_P);
  u16* H = (u16*)(ws + OFF_HST);
  float* C = (float*)(ws + OFF_CSTATE);
  const float* SC = (const float*)(ws + OFF_SC);
  unsigned* flags = (unsigned*)(ws + OFF_BAR);

  __shared__ __align__(16) u16 alds[4][16][64][8];  // 64KB phase-A weights, read order
  __shared__ float red[4][4][16][16];               // 4KB reduction buffer
  __shared__ int bar_ok;

  // phase-A wave-unit decode (fixed across ticks): 4m x 4g x 32ft x 2bh = 1024
  const int u = bid * 4 + wave;
  const int A_bh = u & 1, A_ft = (u >> 1) & 31, A_g = (u >> 6) & 3, A_m = u >> 8;
  // phase-B block decode: 2L x 4j x 32ht = 256
  const int B_L = bid >> 7, B_j = (bid >> 5) & 3, B_ht = bid & 31;

  if (tid == 0) bar_ok = 1;

  // ---- one-time preloads (constant across all 1024 ticks) ----
  // phase-A weight slice -> LDS in exact per-lane read order.
  const int fcol = A_ft * 16 + l16;
  {
    const u16* Bp = (const u16*)(ws + (size_t)A_m * WT_BYTES) +
                    (((size_t)A_g * 512 + fcol) << 9);
#pragma unroll
    for (int kk = 0; kk < 16; ++kk) {
      s16x8 w = *(const s16x8*)(Bp + kk * 32 + q * 8);
      *(s16x8*)&alds[wave][kk][lane][0] = w;
    }
  }
  // phase-B weight slice -> registers (32 x s16x8 = 128 VGPRs, static index only)
  s16x8 wreg[32];
  {
    const int xp = wave >> 1, fbase = (wave & 1) * 256;
    const u16* Wt = (const u16*)(ws + (size_t)(4 + B_L * 2 + xp) * WT_BYTES);
#pragma unroll
    for (int g = 0; g < 4; ++g)
#pragma unroll
      for (int kk = 0; kk < 8; ++kk)
        wreg[g * 8 + kk] = *(const s16x8*)(
            Wt + (((size_t)(g * 512 + B_ht * 16 + l16)) << 9) + fbase + kk * 32 + q * 8);
  }
  // phase-A scale slice -> registers (8 floats/lane)
  float scv[8];
  {
    const size_t mg = (size_t)(A_m * 4 + A_g) * 64;
    const float* sc = SC + (mg << 9) + fcol;
#pragma unroll
    for (int r = 0; r < 4; ++r) {
      scv[r]     = sc[(size_t)(A_bh * 32 + q * 4 + r) << 9];
      scv[4 + r] = sc[(size_t)(A_bh * 32 + q * 4 + r + 16) << 9];
    }
  }
  // phase-B bias -> registers (4 floats/thread)
  const int erow = tid >> 4, ecol = tid & 15;
  const int eb = B_j * 16 + erow, eh = B_ht * 16 + ecol;
  float bv[4];
  {
    const float* bias = (B_L == 0) ? bias0 : bias1;
#pragma unroll
    for (int g = 0; g < 4; ++g) bv[g] = bias[g * 512 + eh];
  }
  __syncthreads();

  unsigned phase = 0;
  for (int tau = 0; tau <= T_; ++tau) {
    // ---------------- phase A : first-stage GEMMs -> P[m] ----------------
    {
      bool act = (A_m < 2) ? (tau < T_) : (tau >= 1);
      if (act) {
        const int row0 = A_bh * 32 + l16, row1 = row0 + 16;
        f32x4 acc0 = {0.f, 0.f, 0.f, 0.f}, acc1 = {0.f, 0.f, 0.f, 0.f};
        if (A_m == 0 && !use_xbf) {  // fallback: x_t fp32 from inps
          const float* x0 = inps + ((size_t)row0 * T_ + tau) * 512;
          const float* x1 = inps + ((size_t)row1 * T_ + tau) * 512;
#pragma unroll 2
          for (int kk = 0; kk < 16; ++kk) {
            int k = kk * 32 + q * 8;
            s16x8 bf = *(const s16x8*)&alds[wave][kk][lane][0];
            acc0 = mfma_bf16(cvt8(x0 + k), bf, acc0);
            acc1 = mfma_bf16(cvt8(x1 + k), bf, acc1);
          }
        } else {  // bf16 A: x (pre-converted) or h0/h1 state
          const u16 *a0p, *a1p;
          if (A_m == 0) {
            const u16* xb = (const u16*)(ws + OFF_XBF);
            a0p = xb + ((size_t)row0 * T_ + tau) * 512;
            a1p = xb + ((size_t)row1 * T_ + tau) * 512;
          } else {
            const u16* hsrc = (A_m == 2) ? (H + 32768) : H;
            a0p = hsrc + row0 * 512;
            a1p = hsrc + row1 * 512;
          }
#pragma unroll 2
          for (int kk = 0; kk < 16; ++kk) {
            int k = kk * 32 + q * 8;
            s16x8 bf = *(const s16x8*)&alds[wave][kk][lane][0];
            s16x8 a0 = *(const s16x8*)(a0p + k);
            s16x8 a1 = *(const s16x8*)(a1p + k);
            acc0 = mfma_bf16(a0, bf, acc0);
            acc1 = mfma_bf16(a1, bf, acc1);
          }
        }
        const size_t mg = (size_t)(A_m * 4 + A_g) * 64;
        u16* Pp = P + (mg << 9) + fcol;
#pragma unroll
        for (int r = 0; r < 4; ++r) {
          int b0r = A_bh * 32 + q * 4 + r;
          Pp[(size_t)b0r << 9] = f2bf(acc0[r] * scv[r]);
          Pp[(size_t)(b0r + 16) << 9] = f2bf(acc1[r] * scv[4 + r]);
        }
      }
      if (!gridbar(flags, ++phase, &bar_ok)) break;
    }
    // ---------------- phase B : second-stage GEMMs + gate epilogue ----------------
    {
      bool act = (B_L == 0) ? (tau < T_) : (tau >= 1);
      if (act) {
        const int xp = (wave < 2) ? 0 : 1;        // 0 = x-path, 1 = h-path
        const int fbase = (wave & 1) * 256;       // K-quarter within the path
        const int Pidx = (B_L == 0) ? xp : (3 - xp);  // L0: P0/P1 ; L1: P3/P2
        const u16* Pm = P + ((size_t)Pidx << 17);
        f32x4 acc[4] = {{0.f,0.f,0.f,0.f},{0.f,0.f,0.f,0.f},
                        {0.f,0.f,0.f,0.f},{0.f,0.f,0.f,0.f}};
        // FULL unroll: wreg[] must be statically indexed (else -> scratch)
#pragma unroll
        for (int kk = 0; kk < 8; ++kk) {
          int k = fbase + kk * 32 + q * 8;
#pragma unroll
          for (int g = 0; g < 4; ++g) {
            s16x8 af = *(const s16x8*)(Pm + ((size_t)((g * 64 + B_j * 16 + l16)) << 9) + k);
            acc[g] = mfma_bf16(af, wreg[g * 8 + kk], acc[g]);
          }
        }
#pragma unroll
        for (int g = 0; g < 4; ++g)
#pragma unroll
          for (int r = 0; r < 4; ++r)
            red[wave][g][q * 4 + r][l16] = acc[g][r];
      }
      __syncthreads();
      if (act) {
        float s[4];
#pragma unroll
        for (int g = 0; g < 4; ++g) {
          float v = bv[g];
          v += red[0][g][erow][ecol] + red[1][g][erow][ecol] +
               red[2][g][erow][ecol] + red[3][g][erow][ecol];
          s[g] = 1.0f / (1.0f + __expf(-v));
        }
        float* cp = C + B_L * 32768 + eb * 512 + eh;
        float cprev = *cp;
        float cn = s[0] * s[3] + s[1] * cprev;
        *cp = cn;
        float hn = s[2] * tanhf(cn);
        H[B_L * 32768 + eb * 512 + eh] = f2bf(hn);
        if (B_L == 1) {
          out[(((size_t)eb * T_ + (tau - 1)) << 9) + eh] = hn;  // out[b][t][h]
          if (tau == T_) {
            out[OUT_HST + eb * 1024 + 512 + eh] = hn;
            out[OUT_CST + eb * 1024 + 512 + eh] = cn;
          }
        } else if (tau == T_ - 1) {
          out[OUT_HST + eb * 1024 + eh] = hn;
          out[OUT_CST + eb * 1024 + eh] = cn;
        }
      }
      if (!gridbar(flags, ++phase, &bar_ok)) break;
    }
  }
}

// ---------------- host launch ----------------

extern "C" void kernel_launch(void* const* d_in, const int* in_sizes, int n_in,
                              void* d_out, int out_size, void* d_ws, size_t ws_size,
                              hipStream_t stream) {
  const float* inps = (const float*)d_in[0];
  const float* hh   = (const float*)d_in[1];
  const float* hc   = (const float*)d_in[2];
  const float* tag  = (const float*)d_in[3];
  const float* Wa0 = (const float*)d_in[4];
  const float* Wb0 = (const float*)d_in[5];
  const float* Wc0 = (const float*)d_in[6];
  const float* Ua0 = (const float*)d_in[7];
  const float* Ub0 = (const float*)d_in[8];
  const float* Uc0 = (const float*)d_in[9];
  const float* b0  = (const float*)d_in[10];
  const float* Wa1 = (const float*)d_in[11];
  const float* Wb1 = (const float*)d_in[12];
  const float* Wc1 = (const float*)d_in[13];
  const float* Ua1 = (const float*)d_in[14];
  const float* Ub1 = (const float*)d_in[15];
  const float* Uc1 = (const float*)d_in[16];
  const float* b1  = (const float*)d_in[17];
  unsigned char* ws = (unsigned char*)d_ws;

  // transposed-weight slot order: [0]=Wc0 [1]=Uc0 [2]=Uc1 [3]=Wc1 (phase A)
  //                               [4]=Wa0 [5]=Ua0 [6]=Wa1 [7]=Ua1 (phase B)
  SrcPtrs sp;
  sp.p[0] = Wc0; sp.p[1] = Uc0; sp.p[2] = Uc1; sp.p[3] = Wc1;
  sp.p[4] = Wa0; sp.p[5] = Ua0; sp.p[6] = Wa1; sp.p[7] = Ua1;

  int use_xbf = (ws_size >= (size_t)OFF_XBF + XBF_BYTES) ? 1 : 0;

  prep_transpose<<<dim3(2048), dim3(256), 0, stream>>>(sp, ws);
  prep_scales<<<dim3(2048), dim3(256), 0, stream>>>(tag, Wb0, Ub0, Ub1, Wb1, ws);
  prep_state<<<dim3(256), dim3(256), 0, stream>>>(hh, hc, ws);
  if (use_xbf)
    prep_xbf16<<<dim3(4096), dim3(256), 0, stream>>>(inps, ws);
  scn_persistent<<<dim3(256), dim3(256), 0, stream>>>(inps, b0, b1, ws,
                                                      (float*)d_out, use_xbf);
}

// Round 4
// 65145.477 us; speedup vs baseline: 1.1258x; 1.1258x over previous
//
// SCN-LSTM persistent-kernel implementation for MI355X (gfx950).
//
// Round 5 (= round-4 design, de-risked):
//  - Round-3 failed with no counters; infra was suspect (round-2 container
//    showed 1686s/1197s npz pushes). Code audit vs the passing round-2 source
//    found no OOB; the only unproven primitive was the split acquire/release
//    fence builtins. This round keeps the NEW hierarchical master barrier but
//    reverts ALL fencing to the known-good __threadfence() + RELEASE-store +
//    RELAXED-load combo that passed in rounds 0/2.
//  - Barrier (master): blocks release-store flags[bid]; ONLY block 0 wave 0
//    polls all 256 flags (2 u64 loads/lane); block 0 then stores 8 per-XCD go
//    words (64B-separated lines); other blocks poll their go word with ONE
//    thread. Contention model: round-0 barrier = 256 pollers on ONE line
//    (~25us service); round-2 = 16K pollers on 16 lines (36us/phase). Here:
//    arrive lines ~0 steady pollers, go lines 31 pollers -> ~1.5us.
//  - Timeout 2^19 polls (~0.15s): even systematic barrier failure bails all
//    blocks in <0.5s per launch; cannot hang the harness.
//  - Kept from round 3: 32-in-flight load buffering in both phases (VGPR ~310,
//    launch_bounds(256,1) -> 512 budget, no spill), red[16][17] padding (kills
//    the 3.35e7 LDS bank conflicts), nontemporal out stores.
#include <hip/hip_runtime.h>

typedef unsigned short u16;
typedef __attribute__((ext_vector_type(8))) short s16x8;
typedef __attribute__((ext_vector_type(4))) float f32x4;
typedef __attribute__((ext_vector_type(4))) float float4v;

#define T_ 1024
#define OUT_HST 33554432   // 64*1024*512
#define OUT_CST 33619968   // + 64*2*512

// workspace byte offsets
#define WT_BYTES   (1u << 21)                // 2MB per transposed weight tensor (4x512x512 bf16)
#define OFF_SC     (8u * WT_BYTES)           // 16,777,216 : tb0, ub0, ub1, tb1 (4x4x64x512 f32)
#define OFF_P      (OFF_SC + 2097152u)       // 18,874,368 : P0..P3 (4 x 4x64x512 bf16)
#define OFF_HST    (OFF_P + 1048576u)        // 19,922,944 : h state, 2 layers, bf16
#define OFF_CSTATE (OFF_HST + 131072u)       // 20,054,016 : c state, 2 layers, f32
#define OFF_BAR    (OFF_CSTATE + 262144u)    // 20,316,160 : barrier flags (4KB: arrive[256], go @ +2KB)
#define OFF_XBF    (OFF_BAR + 4096u)         // 20,320,256 : inps as bf16 (optional)
#define XBF_BYTES  67108864ull               // 64*1024*512*2

__device__ __forceinline__ u16 f2bf(float f) {
  union { float f; unsigned u; } v; v.f = f;
  return (u16)((v.u + 0x7FFFu + ((v.u >> 16) & 1u)) >> 16);
}

__device__ __forceinline__ s16x8 cvt8(const float* p) {
  float4v a = *(const float4v*)p;
  float4v b = *(const float4v*)(p + 4);
  s16x8 r;
  r[0] = (short)f2bf(a[0]); r[1] = (short)f2bf(a[1]);
  r[2] = (short)f2bf(a[2]); r[3] = (short)f2bf(a[3]);
  r[4] = (short)f2bf(b[0]); r[5] = (short)f2bf(b[1]);
  r[6] = (short)f2bf(b[2]); r[7] = (short)f2bf(b[3]);
  return r;
}

__device__ __forceinline__ f32x4 mfma_bf16(s16x8 a, s16x8 b, f32x4 c) {
  return __builtin_amdgcn_mfma_f32_16x16x32_bf16(a, b, c, 0, 0, 0);
}

// ---------------- prep kernels ----------------

struct SrcPtrs { const float* p[8]; };

// Transpose 8 weight tensors (4,512,512) f32 [g][k][n] -> (4,512,512) bf16 [g][n][k]
__global__ void prep_transpose(SrcPtrs s, unsigned char* ws) {
  __shared__ float tb[64][65];
  int bid = blockIdx.x, tid = threadIdx.x;
  int ten = bid >> 8, g = (bid >> 6) & 3, tile = bid & 63;
  int tk = (tile >> 3) << 6, tn = (tile & 7) << 6;
  const float* src = s.p[ten] + ((size_t)g << 18);
  u16* dst = (u16*)(ws + (size_t)ten * WT_BYTES) + ((size_t)g << 18);
  int c = tid & 63, i0 = tid >> 6;
  for (int i = i0; i < 64; i += 4)
    tb[i][c] = src[(size_t)(tk + i) * 512 + tn + c];
  __syncthreads();
  for (int i = i0; i < 64; i += 4)
    dst[(size_t)(tn + i) * 512 + tk + c] = f2bf(tb[c][i]);
}

// SC[m][g][b][f] = sum_k tag[b][k] * W_m[g][k][f], K=300.  m: tb0, ub0, ub1, tb1
__global__ void prep_scales(const float* tag, const float* w0, const float* w1,
                            const float* w2, const float* w3, unsigned char* ws) {
  int t = blockIdx.x * 256 + threadIdx.x;
  int f = t & 511, b = (t >> 9) & 63, g = (t >> 15) & 3, m = t >> 17;
  const float* W = (m == 0) ? w0 : (m == 1) ? w1 : (m == 2) ? w2 : w3;
  const float* tg = tag + b * 300;
  const float* wp = W + (size_t)(g * 300) * 512 + f;
  float acc = 0.f;
  for (int k = 0; k < 300; ++k) acc += tg[k] * wp[(size_t)k * 512];
  ((float*)(ws + OFF_SC))[((size_t)(m * 4 + g) * 64 + b) * 512 + f] = acc;
}

// init h/c state + barrier flags
__global__ void prep_state(const float* hh, const float* hc, unsigned char* ws) {
  int t = blockIdx.x * 256 + threadIdx.x;  // 0..65535
  u16* H = (u16*)(ws + OFF_HST);
  float* C = (float*)(ws + OFF_CSTATE);
  unsigned* bar = (unsigned*)(ws + OFF_BAR);
  if (t < 1024) bar[t] = 0u;
  int L = t >> 15, r = t & 32767;
  int b = r >> 9, h = r & 511;
  float hv = hh[(size_t)b * 1024 + L * 512 + h];
  float cv = hc[(size_t)b * 1024 + L * 512 + h];
  H[t] = f2bf(hv);
  C[t] = cv;
}

// convert inps (64,1024,512) f32 -> bf16 in ws (same layout).
// 33,554,432 elements = 4,194,304 groups of 8.
__global__ void prep_xbf16(const float* __restrict__ inps, unsigned char* ws) {
  u16* dst = (u16*)(ws + OFF_XBF);
  size_t stride = (size_t)gridDim.x * blockDim.x;
  for (size_t i = (size_t)blockIdx.x * blockDim.x + threadIdx.x; i < 4194304ull;
       i += stride)
    *(s16x8*)(dst + i * 8) = cvt8(inps + i * 8);
}

// ---------------- persistent kernel ----------------

// Hierarchical master barrier, known-good memory primitives only:
//  arrive: __threadfence() + RELEASE store flags[bid]=phase (round-0/2 combo).
//  block 0, wave 0: RELAXED-polls all 256 flags (2 u64 loads/lane), then
//    lanes 0..7 RELEASE-store go[lane*16]=phase (8 separate cachelines).
//  other blocks: thread 0 RELAXED-polls go[(bid&7)*16].
//  depart: __threadfence() (invalidate stale L1/L2 before reading peer data).
__device__ __forceinline__ bool gridbar(unsigned* flags, unsigned phase,
                                        int* okflag) {
  unsigned* go = flags + 512;  // +2KB
  __syncthreads();
  if (threadIdx.x == 0) {
    __threadfence();
    __hip_atomic_store(flags + blockIdx.x, phase, __ATOMIC_RELEASE,
                       __HIP_MEMORY_SCOPE_AGENT);
  }
  if (blockIdx.x == 0) {
    if (threadIdx.x < 64) {
      const unsigned long long* fp =
          (const unsigned long long*)flags + (size_t)threadIdx.x * 2;
      long spin = 0;
      for (;;) {
        unsigned long long v0 =
            __hip_atomic_load(fp + 0, __ATOMIC_RELAXED, __HIP_MEMORY_SCOPE_AGENT);
        unsigned long long v1 =
            __hip_atomic_load(fp + 1, __ATOMIC_RELAXED, __HIP_MEMORY_SCOPE_AGENT);
        if ((unsigned)v0 >= phase && (unsigned)(v0 >> 32) >= phase &&
            (unsigned)v1 >= phase && (unsigned)(v1 >> 32) >= phase)
          break;
        __builtin_amdgcn_s_sleep(1);
        if (++spin > (1L << 19)) { *okflag = 0; break; }  // ~0.15s: bail
      }
    }
    __syncthreads();
    if (threadIdx.x < 8)
      __hip_atomic_store(go + threadIdx.x * 16, phase, __ATOMIC_RELEASE,
                         __HIP_MEMORY_SCOPE_AGENT);
  } else {
    if (threadIdx.x == 0) {
      unsigned* gp = go + (blockIdx.x & 7) * 16;
      long spin = 0;
      while (__hip_atomic_load(gp, __ATOMIC_RELAXED, __HIP_MEMORY_SCOPE_AGENT) <
             phase) {
        __builtin_amdgcn_s_sleep(1);
        if (++spin > (1L << 19)) { *okflag = 0; break; }
      }
    }
  }
  __syncthreads();
  __threadfence();
  return *okflag != 0;
}

__global__ __launch_bounds__(256, 1) void scn_persistent(
    const float* __restrict__ inps, const float* __restrict__ bias0,
    const float* __restrict__ bias1, unsigned char* __restrict__ ws,
    float* __restrict__ out, int use_xbf) {
  const int tid = threadIdx.x;
  const int wave = tid >> 6, lane = tid & 63, q = lane >> 4, l16 = lane & 15;
  const int bid = blockIdx.x;

  u16* P = (u16*)(ws + OFF_P);
  u16* H = (u16*)(ws + OFF_HST);
  float* C = (float*)(ws + OFF_CSTATE);
  const float* SC = (const float*)(ws + OFF_SC);
  unsigned* flags = (unsigned*)(ws + OFF_BAR);

  __shared__ __align__(16) u16 alds[4][16][64][8];  // 64KB phase-A weights, read order
  __shared__ float red[4][4][16][17];               // 17KB, padded: no bank conflict
  __shared__ int bar_ok;

  // phase-A wave-unit decode (fixed across ticks): 4m x 4g x 32ft x 2bh = 1024
  const int u = bid * 4 + wave;
  const int A_bh = u & 1, A_ft = (u >> 1) & 31, A_g = (u >> 6) & 3, A_m = u >> 8;
  // phase-B block decode: 2L x 4j x 32ht = 256
  const int B_L = bid >> 7, B_j = (bid >> 5) & 3, B_ht = bid & 31;

  if (tid == 0) bar_ok = 1;

  // ---- one-time preloads (constant across all 1024 ticks) ----
  // phase-A weight slice -> LDS in exact per-lane read order.
  const int fcol = A_ft * 16 + l16;
  {
    const u16* Bp = (const u16*)(ws + (size_t)A_m * WT_BYTES) +
                    (((size_t)A_g * 512 + fcol) << 9);
#pragma unroll
    for (int kk = 0; kk < 16; ++kk) {
      s16x8 w = *(const s16x8*)(Bp + kk * 32 + q * 8);
      *(s16x8*)&alds[wave][kk][lane][0] = w;
    }
  }
  // phase-B weight slice -> registers (32 x s16x8 = 128 VGPRs, static index only)
  s16x8 wreg[32];
  {
    const int xp = wave >> 1, fbase = (wave & 1) * 256;
    const u16* Wt = (const u16*)(ws + (size_t)(4 + B_L * 2 + xp) * WT_BYTES);
#pragma unroll
    for (int g = 0; g < 4; ++g)
#pragma unroll
      for (int kk = 0; kk < 8; ++kk)
        wreg[g * 8 + kk] = *(const s16x8*)(
            Wt + (((size_t)(g * 512 + B_ht * 16 + l16)) << 9) + fbase + kk * 32 + q * 8);
  }
  // phase-A scale slice -> registers (8 floats/lane)
  float scv[8];
  {
    const size_t mg = (size_t)(A_m * 4 + A_g) * 64;
    const float* sc = SC + (mg << 9) + fcol;
#pragma unroll
    for (int r = 0; r < 4; ++r) {
      scv[r]     = sc[(size_t)(A_bh * 32 + q * 4 + r) << 9];
      scv[4 + r] = sc[(size_t)(A_bh * 32 + q * 4 + r + 16) << 9];
    }
  }
  // phase-B bias -> registers (4 floats/thread)
  const int erow = tid >> 4, ecol = tid & 15;
  const int eb = B_j * 16 + erow, eh = B_ht * 16 + ecol;
  float bv[4];
  {
    const float* bias = (B_L == 0) ? bias0 : bias1;
#pragma unroll
    for (int g = 0; g < 4; ++g) bv[g] = bias[g * 512 + eh];
  }
  __syncthreads();

  unsigned phase = 0;
  for (int tau = 0; tau <= T_; ++tau) {
    // ---------------- phase A : first-stage GEMMs -> P[m] ----------------
    {
      bool act = (A_m < 2) ? (tau < T_) : (tau >= 1);
      if (act) {
        const int row0 = A_bh * 32 + l16, row1 = row0 + 16;
        f32x4 acc0 = {0.f, 0.f, 0.f, 0.f}, acc1 = {0.f, 0.f, 0.f, 0.f};
        if (A_m == 0 && !use_xbf) {  // fallback: x_t fp32 from inps
          const float* x0 = inps + ((size_t)row0 * T_ + tau) * 512;
          const float* x1 = inps + ((size_t)row1 * T_ + tau) * 512;
#pragma unroll 2
          for (int kk = 0; kk < 16; ++kk) {
            int k = kk * 32 + q * 8;
            s16x8 bf = *(const s16x8*)&alds[wave][kk][lane][0];
            acc0 = mfma_bf16(cvt8(x0 + k), bf, acc0);
            acc1 = mfma_bf16(cvt8(x1 + k), bf, acc1);
          }
        } else {  // bf16 A: x (pre-converted) or h0/h1 state
          const u16 *a0p, *a1p;
          if (A_m == 0) {
            const u16* xb = (const u16*)(ws + OFF_XBF);
            a0p = xb + ((size_t)row0 * T_ + tau) * 512;
            a1p = xb + ((size_t)row1 * T_ + tau) * 512;
          } else {
            const u16* hsrc = (A_m == 2) ? (H + 32768) : H;
            a0p = hsrc + row0 * 512;
            a1p = hsrc + row1 * 512;
          }
          // buffer ALL 32 fragments -> 32 loads in flight (one L3 latency total)
          s16x8 U[16], V[16];
#pragma unroll
          for (int kk = 0; kk < 16; ++kk) {
            U[kk] = *(const s16x8*)(a0p + kk * 32 + q * 8);
            V[kk] = *(const s16x8*)(a1p + kk * 32 + q * 8);
          }
#pragma unroll
          for (int kk = 0; kk < 16; ++kk) {
            s16x8 bf = *(const s16x8*)&alds[wave][kk][lane][0];
            acc0 = mfma_bf16(U[kk], bf, acc0);
            acc1 = mfma_bf16(V[kk], bf, acc1);
          }
        }
        const size_t mg = (size_t)(A_m * 4 + A_g) * 64;
        u16* Pp = P + (mg << 9) + fcol;
#pragma unroll
        for (int r = 0; r < 4; ++r) {
          int b0r = A_bh * 32 + q * 4 + r;
          Pp[(size_t)b0r << 9] = f2bf(acc0[r] * scv[r]);
          Pp[(size_t)(b0r + 16) << 9] = f2bf(acc1[r] * scv[4 + r]);
        }
      }
      if (!gridbar(flags, ++phase, &bar_ok)) break;
    }
    // ---------------- phase B : second-stage GEMMs + gate epilogue ----------------
    {
      bool act = (B_L == 0) ? (tau < T_) : (tau >= 1);
      if (act) {
        const int xp = (wave < 2) ? 0 : 1;        // 0 = x-path, 1 = h-path
        const int fbase = (wave & 1) * 256;       // K-quarter within the path
        const int Pidx = (B_L == 0) ? xp : (3 - xp);  // L0: P0/P1 ; L1: P3/P2
        const u16* Pm = P + ((size_t)Pidx << 17);
        const u16* Pb = Pm + (((size_t)(B_j * 16 + l16)) << 9) + fbase + q * 8;
        f32x4 acc[4] = {{0.f,0.f,0.f,0.f},{0.f,0.f,0.f,0.f},
                        {0.f,0.f,0.f,0.f},{0.f,0.f,0.f,0.f}};
        // buffer ALL 32 P fragments (128 VGPRs) -> 32 loads in flight
        s16x8 AF[8][4];
#pragma unroll
        for (int kk = 0; kk < 8; ++kk)
#pragma unroll
          for (int g = 0; g < 4; ++g)
            AF[kk][g] = *(const s16x8*)(Pb + ((size_t)g << 15) + kk * 32);
#pragma unroll
        for (int kk = 0; kk < 8; ++kk)
#pragma unroll
          for (int g = 0; g < 4; ++g)
            acc[g] = mfma_bf16(AF[kk][g], wreg[g * 8 + kk], acc[g]);
#pragma unroll
        for (int g = 0; g < 4; ++g)
#pragma unroll
          for (int r = 0; r < 4; ++r)
            red[wave][g][q * 4 + r][l16] = acc[g][r];
      }
      __syncthreads();
      if (act) {
        float s[4];
#pragma unroll
        for (int g = 0; g < 4; ++g) {
          float v = bv[g];
          v += red[0][g][erow][ecol] + red[1][g][erow][ecol] +
               red[2][g][erow][ecol] + red[3][g][erow][ecol];
          s[g] = 1.0f / (1.0f + __expf(-v));
        }
        float* cp = C + B_L * 32768 + eb * 512 + eh;
        float cprev = *cp;
        float cn = s[0] * s[3] + s[1] * cprev;
        *cp = cn;
        float hn = s[2] * tanhf(cn);
        H[B_L * 32768 + eb * 512 + eh] = f2bf(hn);
        if (B_L == 1) {
          __builtin_nontemporal_store(hn, &out[(((size_t)eb * T_ + (tau - 1)) << 9) + eh]);
          if (tau == T_) {
            __builtin_nontemporal_store(hn, &out[OUT_HST + eb * 1024 + 512 + eh]);
            __builtin_nontemporal_store(cn, &out[OUT_CST + eb * 1024 + 512 + eh]);
          }
        } else if (tau == T_ - 1) {
          __builtin_nontemporal_store(hn, &out[OUT_HST + eb * 1024 + eh]);
          __builtin_nontemporal_store(cn, &out[OUT_CST + eb * 1024 + eh]);
        }
      }
      if (!gridbar(flags, ++phase, &bar_ok)) break;
    }
  }
}

// ---------------- host launch ----------------

extern "C" void kernel_launch(void* const* d_in, const int* in_sizes, int n_in,
                              void* d_out, int out_size, void* d_ws, size_t ws_size,
                              hipStream_t stream) {
  const float* inps = (const float*)d_in[0];
  const float* hh   = (const float*)d_in[1];
  const float* hc   = (const float*)d_in[2];
  const float* tag  = (const float*)d_in[3];
  const float* Wa0 = (const float*)d_in[4];
  const float* Wb0 = (const float*)d_in[5];
  const float* Wc0 = (const float*)d_in[6];
  const float* Ua0 = (const float*)d_in[7];
  const float* Ub0 = (const float*)d_in[8];
  const float* Uc0 = (const float*)d_in[9];
  const float* b0  = (const float*)d_in[10];
  const float* Wa1 = (const float*)d_in[11];
  const float* Wb1 = (const float*)d_in[12];
  const float* Wc1 = (const float*)d_in[13];
  const float* Ua1 = (const float*)d_in[14];
  const float* Ub1 = (const float*)d_in[15];
  const float* Uc1 = (const float*)d_in[16];
  const float* b1  = (const float*)d_in[17];
  unsigned char* ws = (unsigned char*)d_ws;

  // transposed-weight slot order: [0]=Wc0 [1]=Uc0 [2]=Uc1 [3]=Wc1 (phase A)
  //                               [4]=Wa0 [5]=Ua0 [6]=Wa1 [7]=Ua1 (phase B)
  SrcPtrs sp;
  sp.p[0] = Wc0; sp.p[1] = Uc0; sp.p[2] = Uc1; sp.p[3] = Wc1;
  sp.p[4] = Wa0; sp.p[5] = Ua0; sp.p[6] = Wa1; sp.p[7] = Ua1;

  int use_xbf = (ws_size >= (size_t)OFF_XBF + XBF_BYTES) ? 1 : 0;

  prep_transpose<<<dim3(2048), dim3(256), 0, stream>>>(sp, ws);
  prep_scales<<<dim3(2048), dim3(256), 0, stream>>>(tag, Wb0, Ub0, Ub1, Wb1, ws);
  prep_state<<<dim3(256), dim3(256), 0, stream>>>(hh, hc, ws);
  if (use_xbf)
    prep_xbf16<<<dim3(4096), dim3(256), 0, stream>>>(inps, ws);
  scn_persistent<<<dim3(256), dim3(256), 0, stream>>>(inps, b0, b1, ws,
                                                      (float*)d_out, use_xbf);
}

// Round 5
// 28558.121 us; speedup vs baseline: 2.5680x; 2.2812x over previous
//
// SCN-LSTM persistent-kernel implementation for MI355X (gfx950).
//
// Round 6 — team restructure:
//  - Post-mortem r4: three different barrier designs all ~30us/phase =>
//    bottleneck is NOT barrier fan-in. Survivors: (a) per-phase L2 wbl2/inv
//    cache maintenance with zero TLP to hide the refill, (b) straggler
//    max-statistics over 256 lockstepped blocks.
//  - Batch rows are independent (only weights shared). New decomposition:
//    4 independent TEAMS x 64 blocks; team owns 16 batch rows. All weights
//    team-resident: stage-1 slice (path p, 32 f-cols) in 64KB LDS + 64 VGPRs;
//    stage-2 slice (layer L, 16 h-cols) in 128 VGPRs.
//  - ZERO fences: all cross-block data (P, H) uses agent-scope RELAXED atomic
//    u32 write-through stores/loads (sc0 sc1 -> L3 coherence point). L2 never
//    caches shared mutable data => no wbl2/buffer_inv anywhere. Arrive =
//    s_waitcnt vmcnt(0) + relaxed flag store (the ISA release recipe for
//    write-through data). c-state lives in ONE register/thread all 1024 ticks.
//  - Team barrier: 64 arrive flags, team-master wave polls (1 flag/lane),
//    1 go word/team. 64 participants, 4 teams slip independently.
//  - bf16 u16 pairs packed into u32 via __shfl_xor(1) for atomic stores.
//  - Timeout-bounded polls: no hang possible; bugs surface as absmax fail.
#include <hip/hip_runtime.h>

typedef unsigned short u16;
typedef __attribute__((ext_vector_type(8))) short s16x8;
typedef __attribute__((ext_vector_type(4))) float f32x4;
typedef __attribute__((ext_vector_type(4))) float float4v;

#define T_ 1024
#define OUT_HST 33554432   // 64*1024*512
#define OUT_CST 33619968   // + 64*2*512

// workspace byte offsets
#define WT_BYTES   (1u << 21)                // 2MB per transposed weight tensor (4x512x512 bf16)
#define OFF_SC     (8u * WT_BYTES)           // 16,777,216 : tb0, ub0, ub1, tb1 (4x4x64x512 f32)
#define OFF_P      (OFF_SC + 2097152u)       // 18,874,368 : P [4tm][4p][4g][16b][512f] bf16 = 1MB
#define OFF_HST    (OFF_P + 1048576u)        // 19,922,944 : h state, 2 layers, bf16 (128KB)
#define OFF_BAR    (OFF_HST + 131072u)       // 20,054,016 : flags, 4 teams x 4KB

__device__ __forceinline__ u16 f2bf(float f) {
  union { float f; unsigned u; } v; v.f = f;
  return (u16)((v.u + 0x7FFFu + ((v.u >> 16) & 1u)) >> 16);
}

__device__ __forceinline__ s16x8 cvt8(const float* p) {
  float4v a = *(const float4v*)p;
  float4v b = *(const float4v*)(p + 4);
  s16x8 r;
  r[0] = (short)f2bf(a[0]); r[1] = (short)f2bf(a[1]);
  r[2] = (short)f2bf(a[2]); r[3] = (short)f2bf(a[3]);
  r[4] = (short)f2bf(b[0]); r[5] = (short)f2bf(b[1]);
  r[6] = (short)f2bf(b[2]); r[7] = (short)f2bf(b[3]);
  return r;
}

__device__ __forceinline__ f32x4 mfma_bf16(s16x8 a, s16x8 b, f32x4 c) {
  return __builtin_amdgcn_mfma_f32_16x16x32_bf16(a, b, c, 0, 0, 0);
}

// write-through coherent u32 store/load (sc0 sc1 -> L3, bypass L1/L2)
__device__ __forceinline__ void st_u32_coh(unsigned* p, unsigned v) {
  __hip_atomic_store(p, v, __ATOMIC_RELAXED, __HIP_MEMORY_SCOPE_AGENT);
}
__device__ __forceinline__ unsigned ld_u32_coh(const unsigned* p) {
  return __hip_atomic_load(p, __ATOMIC_RELAXED, __HIP_MEMORY_SCOPE_AGENT);
}
__device__ __forceinline__ s16x8 ld_bf16x8_coh(const unsigned* p) {
  union { unsigned u[4]; s16x8 v; } r;
#pragma unroll
  for (int i = 0; i < 4; ++i) r.u[i] = ld_u32_coh(p + i);
  return r.v;
}

// ---------------- prep kernels ----------------

struct SrcPtrs { const float* p[8]; };

// Transpose 8 weight tensors (4,512,512) f32 [g][k][n] -> (4,512,512) bf16 [g][n][k]
__global__ void prep_transpose(SrcPtrs s, unsigned char* ws) {
  __shared__ float tb[64][65];
  int bid = blockIdx.x, tid = threadIdx.x;
  int ten = bid >> 8, g = (bid >> 6) & 3, tile = bid & 63;
  int tk = (tile >> 3) << 6, tn = (tile & 7) << 6;
  const float* src = s.p[ten] + ((size_t)g << 18);
  u16* dst = (u16*)(ws + (size_t)ten * WT_BYTES) + ((size_t)g << 18);
  int c = tid & 63, i0 = tid >> 6;
  for (int i = i0; i < 64; i += 4)
    tb[i][c] = src[(size_t)(tk + i) * 512 + tn + c];
  __syncthreads();
  for (int i = i0; i < 64; i += 4)
    dst[(size_t)(tn + i) * 512 + tk + c] = f2bf(tb[c][i]);
}

// SC[m][g][b][f] = sum_k tag[b][k] * W_m[g][k][f], K=300.  m: tb0, ub0, ub1, tb1
__global__ void prep_scales(const float* tag, const float* w0, const float* w1,
                            const float* w2, const float* w3, unsigned char* ws) {
  int t = blockIdx.x * 256 + threadIdx.x;
  int f = t & 511, b = (t >> 9) & 63, g = (t >> 15) & 3, m = t >> 17;
  const float* W = (m == 0) ? w0 : (m == 1) ? w1 : (m == 2) ? w2 : w3;
  const float* tg = tag + b * 300;
  const float* wp = W + (size_t)(g * 300) * 512 + f;
  float acc = 0.f;
  for (int k = 0; k < 300; ++k) acc += tg[k] * wp[(size_t)k * 512];
  ((float*)(ws + OFF_SC))[((size_t)(m * 4 + g) * 64 + b) * 512 + f] = acc;
}

// init h state (bf16) + zero barrier flags (16KB)
__global__ void prep_state(const float* hh, unsigned char* ws) {
  int t = blockIdx.x * 256 + threadIdx.x;  // 0..65535
  u16* H = (u16*)(ws + OFF_HST);
  unsigned* bar = (unsigned*)(ws + OFF_BAR);
  if (t < 4096) bar[t] = 0u;
  int L = t >> 15, r = t & 32767;
  int b = r >> 9, h = r & 511;
  H[t] = f2bf(hh[(size_t)b * 1024 + L * 512 + h]);
}

// ---------------- persistent kernel ----------------

// Team barrier (64 blocks). All shared-data stores are write-through (sc1),
// so release = s_waitcnt vmcnt(0) + relaxed flag store; no cache maintenance.
__device__ __forceinline__ bool teambar(unsigned* tflags, unsigned phase,
                                        int* okflag, int rank) {
  __syncthreads();  // compiler drains vmcnt/lgkmcnt before s_barrier
  asm volatile("s_waitcnt vmcnt(0)" ::: "memory");  // sc1 data at L3
  if (threadIdx.x == 0) st_u32_coh(tflags + rank, phase);
  if (rank == 0) {
    if (threadIdx.x < 64) {
      long spin = 0;
      while (ld_u32_coh(tflags + threadIdx.x) < phase) {
        __builtin_amdgcn_s_sleep(1);
        if (++spin > (1L << 19)) { *okflag = 0; break; }  // ~0.15s: bail
      }
    }
    __syncthreads();
    if (threadIdx.x == 0) st_u32_coh(tflags + 128, phase);  // go word
  } else if (threadIdx.x == 0) {
    long spin = 0;
    while (ld_u32_coh(tflags + 128) < phase) {
      __builtin_amdgcn_s_sleep(1);
      if (++spin > (1L << 19)) { *okflag = 0; break; }
    }
  }
  __syncthreads();
  return *okflag != 0;
}

__global__ __launch_bounds__(256, 1) void scn_persistent(
    const float* __restrict__ inps, const float* __restrict__ hc,
    const float* __restrict__ bias0, const float* __restrict__ bias1,
    unsigned char* __restrict__ ws, float* __restrict__ out) {
  const int tid = threadIdx.x;
  const int wave = tid >> 6, lane = tid & 63, q = lane >> 4, l16 = lane & 15;
  const int bid = blockIdx.x;
  const int tm = bid >> 6, rank = bid & 63;      // team, rank-in-team
  // stage-1 role: path p (0=x@Wc0, 1=h0@Uc0, 2=h1@Uc1, 3=h0@Wc1), f-slice of 32
  const int p = rank >> 4, fs = rank & 15;
  // stage-2 role: layer L, h-slice of 16
  const int L2i = rank >> 5, ht = rank & 31;
  const int pA = L2i ? 3 : 0, pB = L2i ? 2 : 1;  // P paths: W-path, U-path

  unsigned* P32 = (unsigned*)(ws + OFF_P);
  unsigned* H32 = (unsigned*)(ws + OFF_HST);
  const float* SC = (const float*)(ws + OFF_SC);
  unsigned* tflags = (unsigned*)(ws + OFF_BAR) + tm * 1024;

  __shared__ __align__(16) u16 s1lds[4][16][64][8];  // 64KB stage-1 weights ftile0
  __shared__ float red[4][16][17];                   // gate exchange (padded)
  __shared__ int bar_ok;
  if (tid == 0) bar_ok = 1;

  // ---- one-time preloads ----
  // stage-1 weights: slot p, gate = wave, f-cols fs*32 + {l16, 16+l16}
  s16x8 s1w[16];
  {
    const u16* Wt = (const u16*)(ws + (size_t)p * WT_BYTES);
    const u16* w0 = Wt + (((size_t)wave * 512 + fs * 32 + l16) << 9);
    const u16* w1 = Wt + (((size_t)wave * 512 + fs * 32 + 16 + l16) << 9);
#pragma unroll
    for (int kk = 0; kk < 16; ++kk) {
      *(s16x8*)&s1lds[wave][kk][lane][0] = *(const s16x8*)(w0 + kk * 32 + q * 8);
      s1w[kk] = *(const s16x8*)(w1 + kk * 32 + q * 8);
    }
  }
  // stage-2 weights: L0: Wa0(slot4)+Ua0(slot5); L1: Wa1(slot6)+Ua1(slot7)
  s16x8 wregA[16], wregB[16];
  {
    const u16* WtA = (const u16*)(ws + (size_t)(4 + 2 * L2i) * WT_BYTES);
    const u16* WtB = (const u16*)(ws + (size_t)(5 + 2 * L2i) * WT_BYTES);
    const size_t coff = ((size_t)wave * 512 + ht * 16 + l16) << 9;
#pragma unroll
    for (int kk = 0; kk < 16; ++kk) {
      wregA[kk] = *(const s16x8*)(WtA + coff + kk * 32 + q * 8);
      wregB[kk] = *(const s16x8*)(WtB + coff + kk * 32 + q * 8);
    }
  }
  // stage-1 tag scales (m == p by construction), 8 floats
  float scv[2][4];
#pragma unroll
  for (int ft = 0; ft < 2; ++ft)
#pragma unroll
    for (int r = 0; r < 4; ++r)
      scv[ft][r] = SC[((size_t)(p * 4 + wave) * 64 + tm * 16 + q * 4 + r) * 512 +
                      fs * 32 + ft * 16 + l16];
  // stage-2 bias + persistent c-register
  const int erow = tid >> 4, ecol = tid & 15;
  const int ebg = tm * 16 + erow, eh = ht * 16 + ecol;
  float bv[4], creg;
  {
    const float* bias = L2i ? bias1 : bias0;
#pragma unroll
    for (int g = 0; g < 4; ++g) bv[g] = bias[g * 512 + eh];
    creg = hc[(size_t)ebg * 1024 + L2i * 512 + eh];
  }
  __syncthreads();

  unsigned phase = 0;
  for (int tau = 0; tau <= T_; ++tau) {
    // ---- stage 1 : P[p] = (src @ Wc/Uc) * scale  (skewed: L0 step tau, L1 step tau-1)
    {
      const bool act = (p < 2) ? (tau < T_) : (tau >= 1);
      if (act) {
        const int brow = tm * 16 + l16;
        f32x4 acc0 = {0.f, 0.f, 0.f, 0.f}, acc1 = {0.f, 0.f, 0.f, 0.f};
        if (p == 0) {  // x_t fp32, cvt to bf16 (read-only: normal loads)
          const float* x0 = inps + ((size_t)brow * T_ + tau) * 512;
#pragma unroll
          for (int kk = 0; kk < 16; ++kk) {
            s16x8 a = cvt8(x0 + kk * 32 + q * 8);
            acc0 = mfma_bf16(a, *(const s16x8*)&s1lds[wave][kk][lane][0], acc0);
            acc1 = mfma_bf16(a, s1w[kk], acc1);
          }
        } else {  // h state: coherent u32 loads (sc1)
          const int hL = (p == 2) ? 1 : 0;
          const unsigned* hp = H32 + (((size_t)hL * 32768 + (size_t)brow * 512) >> 1) + q * 4;
#pragma unroll
          for (int kk = 0; kk < 16; ++kk) {
            s16x8 a = ld_bf16x8_coh(hp + kk * 16);
            acc0 = mfma_bf16(a, *(const s16x8*)&s1lds[wave][kk][lane][0], acc0);
            acc1 = mfma_bf16(a, s1w[kk], acc1);
          }
        }
        // scale, cvt, pack bf16 pairs across lane^1, write-through store
        const size_t prow = (size_t)(((tm * 4 + p) * 4 + wave) * 16);
#pragma unroll
        for (int ft = 0; ft < 2; ++ft) {
          f32x4 a = ft ? acc1 : acc0;
#pragma unroll
          for (int r = 0; r < 4; ++r) {
            unsigned mybf = f2bf(a[r] * scv[ft][r]);
            unsigned nb = (unsigned)__shfl_xor((int)mybf, 1);
            if ((l16 & 1) == 0) {
              unsigned f = (unsigned)(fs * 32 + ft * 16 + l16);
              st_u32_coh(P32 + (prow + q * 4 + r) * 256 + (f >> 1), mybf | (nb << 16));
            }
          }
        }
      }
      if (!teambar(tflags, ++phase, &bar_ok, rank)) break;
    }
    // ---- stage 2 : gates = P_W @ Wa + P_U @ Ua + b ; cell update ----
    {
      const bool act = (L2i == 0) ? (tau < T_) : (tau >= 1);
      if (act) {
        const size_t pbA = (size_t)(((tm * 4 + pA) * 4 + wave) * 16 + l16) * 256 + q * 4;
        const size_t pbB = (size_t)(((tm * 4 + pB) * 4 + wave) * 16 + l16) * 256 + q * 4;
        f32x4 acc = {0.f, 0.f, 0.f, 0.f};
#pragma unroll
        for (int kk = 0; kk < 16; ++kk) {
          s16x8 a0 = ld_bf16x8_coh(P32 + pbA + kk * 16);
          s16x8 a1 = ld_bf16x8_coh(P32 + pbB + kk * 16);
          acc = mfma_bf16(a0, wregA[kk], acc);
          acc = mfma_bf16(a1, wregB[kk], acc);
        }
#pragma unroll
        for (int r = 0; r < 4; ++r) red[wave][q * 4 + r][l16] = acc[r];
      }
      __syncthreads();
      if (act) {
        float s[4];
#pragma unroll
        for (int g = 0; g < 4; ++g) {
          float v = bv[g] + red[g][erow][ecol];
          s[g] = 1.0f / (1.0f + __expf(-v));
        }
        creg = s[0] * s[3] + s[1] * creg;
        float hn = s[2] * tanhf(creg);
        // h -> write-through (consumed by team's stage-1 next tick)
        unsigned hb = f2bf(hn);
        unsigned nb = (unsigned)__shfl_xor((int)hb, 1);
        if ((tid & 1) == 0)
          st_u32_coh(H32 + (((size_t)L2i * 32768 + (size_t)ebg * 512 + eh) >> 1),
                     hb | (nb << 16));
        if (L2i == 1) {
          __builtin_nontemporal_store(hn, &out[((size_t)ebg * T_ + (tau - 1)) * 512 + eh]);
          if (tau == T_) {
            __builtin_nontemporal_store(hn, &out[OUT_HST + ebg * 1024 + 512 + eh]);
            __builtin_nontemporal_store(creg, &out[OUT_CST + ebg * 1024 + 512 + eh]);
          }
        } else if (tau == T_ - 1) {
          __builtin_nontemporal_store(hn, &out[OUT_HST + ebg * 1024 + eh]);
          __builtin_nontemporal_store(creg, &out[OUT_CST + ebg * 1024 + eh]);
        }
      }
      if (!teambar(tflags, ++phase, &bar_ok, rank)) break;
    }
  }
}

// ---------------- host launch ----------------

extern "C" void kernel_launch(void* const* d_in, const int* in_sizes, int n_in,
                              void* d_out, int out_size, void* d_ws, size_t ws_size,
                              hipStream_t stream) {
  const float* inps = (const float*)d_in[0];
  const float* hh   = (const float*)d_in[1];
  const float* hc   = (const float*)d_in[2];
  const float* tag  = (const float*)d_in[3];
  const float* Wa0 = (const float*)d_in[4];
  const float* Wb0 = (const float*)d_in[5];
  const float* Wc0 = (const float*)d_in[6];
  const float* Ua0 = (const float*)d_in[7];
  const float* Ub0 = (const float*)d_in[8];
  const float* Uc0 = (const float*)d_in[9];
  const float* b0  = (const float*)d_in[10];
  const float* Wa1 = (const float*)d_in[11];
  const float* Wb1 = (const float*)d_in[12];
  const float* Wc1 = (const float*)d_in[13];
  const float* Ua1 = (const float*)d_in[14];
  const float* Ub1 = (const float*)d_in[15];
  const float* Uc1 = (const float*)d_in[16];
  const float* b1  = (const float*)d_in[17];
  unsigned char* ws = (unsigned char*)d_ws;

  // transposed-weight slot order: [0]=Wc0 [1]=Uc0 [2]=Uc1 [3]=Wc1 (stage 1)
  //                               [4]=Wa0 [5]=Ua0 [6]=Wa1 [7]=Ua1 (stage 2)
  SrcPtrs sp;
  sp.p[0] = Wc0; sp.p[1] = Uc0; sp.p[2] = Uc1; sp.p[3] = Wc1;
  sp.p[4] = Wa0; sp.p[5] = Ua0; sp.p[6] = Wa1; sp.p[7] = Ua1;

  prep_transpose<<<dim3(2048), dim3(256), 0, stream>>>(sp, ws);
  prep_scales<<<dim3(2048), dim3(256), 0, stream>>>(tag, Wb0, Ub0, Ub1, Wb1, ws);
  prep_state<<<dim3(256), dim3(256), 0, stream>>>(hh, ws);
  scn_persistent<<<dim3(256), dim3(256), 0, stream>>>(inps, hc, b0, b1, ws,
                                                      (float*)d_out);
}